// Round 1
// baseline (631.900 us; speedup 1.0000x reference)
//
#include <hip/hip_runtime.h>
#include <hip/hip_bf16.h>

#define S_DIM 1024
#define INNER 32
#define PAIR  128
#define LSEQ  1024

// ---------------------------------------------------------------------------
// Kernel 1: per-row LayerNorm + projection to 64 (q|k), plus the separable
// "diff" term precomputation: Aq = q @ W2, Ak = k @ W2  (W2 = o_w[32:64,:]).
// One block per sequence row. 256 threads.
// ---------------------------------------------------------------------------
__global__ __launch_bounds__(256) void ln_proj_kernel(
    const float* __restrict__ x,      // (1024, 1024)
    const float* __restrict__ gamma,  // (1024)
    const float* __restrict__ beta,   // (1024)
    const float* __restrict__ pw,     // (1024, 64)
    const float* __restrict__ pb,     // (64)
    const float* __restrict__ ow,     // (64, 128)
    float* __restrict__ qk,           // (1024, 64)  q=cols 0..31, k=cols 32..63
    float* __restrict__ Aq,           // (1024, 128)
    float* __restrict__ Ak)           // (1024, 128)
{
    const int row  = blockIdx.x;
    const int t    = threadIdx.x;
    const int lane = t & 63;
    const int wv   = t >> 6;

    __shared__ float s_sh[S_DIM];
    __shared__ float wsum[4], wsum2[4];
    __shared__ float hpart[4][64];
    __shared__ float h_sh[64];

    // --- load 4 elements per thread, accumulate sums ---
    float4 xv = ((const float4*)(x + (size_t)row * S_DIM))[t];
    float sum = xv.x + xv.y + xv.z + xv.w;
    float sq  = xv.x*xv.x + xv.y*xv.y + xv.z*xv.z + xv.w*xv.w;
    #pragma unroll
    for (int off = 32; off; off >>= 1) {
        sum += __shfl_down(sum, off, 64);
        sq  += __shfl_down(sq,  off, 64);
    }
    if (lane == 0) { wsum[wv] = sum; wsum2[wv] = sq; }
    __syncthreads();
    float tot  = wsum[0] + wsum[1] + wsum[2] + wsum[3];
    float tot2 = wsum2[0] + wsum2[1] + wsum2[2] + wsum2[3];
    float mu   = tot * (1.0f / S_DIM);
    float var  = tot2 * (1.0f / S_DIM) - mu * mu;
    float rstd = rsqrtf(var + 1e-5f);

    float4 gv = ((const float4*)gamma)[t];
    float4 bv = ((const float4*)beta)[t];
    float4 sv;
    sv.x = (xv.x - mu) * rstd * gv.x + bv.x;
    sv.y = (xv.y - mu) * rstd * gv.y + bv.y;
    sv.z = (xv.z - mu) * rstd * gv.z + bv.z;
    sv.w = (xv.w - mu) * rstd * gv.w + bv.w;
    ((float4*)s_sh)[t] = sv;
    __syncthreads();

    // --- projection: h[c] = sum_d s[d] * pw[d,c] ; split d over 4 waves ---
    {
        const int c    = lane;     // 0..63 output column
        const int part = wv;       // 0..3
        const int dbase = part * 256;
        const float* pwp = pw + c;
        float acc = 0.f;
        for (int d = 0; d < 256; ++d) {
            acc = fmaf(s_sh[dbase + d], pwp[(size_t)(dbase + d) * 64], acc);
        }
        hpart[part][c] = acc;
    }
    __syncthreads();
    if (t < 64) {
        float h = hpart[0][t] + hpart[1][t] + hpart[2][t] + hpart[3][t] + pb[t];
        h_sh[t] = h;
        qk[(size_t)row * 64 + t] = h;
    }
    __syncthreads();

    // --- Aq[row,p] = sum_{c<32} q[c]*W2[c,p] ;  Ak likewise with k ---
    {
        const int p    = t & 127;
        const int half = t >> 7;              // 0 -> Aq, 1 -> Ak
        const float* w2 = ow + 32 * PAIR + p; // W2 base
        const float* hh = h_sh + half * 32;
        float acc = 0.f;
        #pragma unroll
        for (int c = 0; c < 32; ++c)
            acc = fmaf(hh[c], w2[(size_t)c * PAIR], acc);
        if (half == 0) Aq[(size_t)row * PAIR + p] = acc;
        else           Ak[(size_t)row * PAIR + p] = acc;
    }
}

// ---------------------------------------------------------------------------
// Kernel 2: out[i,j,p] = sum_{c<32} q[j,c]*k[i,c]*W1[c,p] + Aq[j,p] - Ak[i,p]
//                        + o_b[p]
// Grid: (1024 i, 8 jblocks). Block: 256 threads = 4 waves; each wave owns
// 32 consecutive j. Each thread owns p = lane and lane+64; kw[c] = k[i,c]*
// W1[c,p] cached in 64 VGPRs so the j-loop is 64 FMA + broadcast q loads.
// ---------------------------------------------------------------------------
__global__ __launch_bounds__(256) void pair_kernel(
    const float* __restrict__ qk,   // (1024, 64)
    const float* __restrict__ Aq,   // (1024, 128)
    const float* __restrict__ Ak,   // (1024, 128)
    const float* __restrict__ ow,   // (64, 128); W1 = rows 0..31
    const float* __restrict__ ob,   // (128)
    float* __restrict__ out)        // (1024, 1024, 128)
{
    const int i    = blockIdx.x;
    const int jblk = blockIdx.y;
    const int lane = threadIdx.x & 63;
    const int wv   = threadIdx.x >> 6;
    const int p0   = lane;
    const int p1   = lane + 64;

    // kw[c] = k[i,c] * W1[c,p] for both owned p's
    float kw0[32], kw1[32];
    const float4* k4 = (const float4*)(qk + (size_t)i * 64 + 32);
    #pragma unroll
    for (int c4 = 0; c4 < 8; ++c4) {
        float4 kv = k4[c4];
        const float* w1 = ow + (size_t)(c4 * 4) * PAIR;
        kw0[c4*4+0] = kv.x * w1[0*PAIR + p0];
        kw1[c4*4+0] = kv.x * w1[0*PAIR + p1];
        kw0[c4*4+1] = kv.y * w1[1*PAIR + p0];
        kw1[c4*4+1] = kv.y * w1[1*PAIR + p1];
        kw0[c4*4+2] = kv.z * w1[2*PAIR + p0];
        kw1[c4*4+2] = kv.z * w1[2*PAIR + p1];
        kw0[c4*4+3] = kv.w * w1[3*PAIR + p0];
        kw1[c4*4+3] = kv.w * w1[3*PAIR + p1];
    }

    const float bias0 = ob[p0] - Ak[(size_t)i * PAIR + p0];
    const float bias1 = ob[p1] - Ak[(size_t)i * PAIR + p1];

    const int jbase = jblk * 128 + wv * 32;
    for (int jj = 0; jj < 32; ++jj) {
        int j = __builtin_amdgcn_readfirstlane(jbase + jj);
        const float4* q4 = (const float4*)(qk + (size_t)j * 64);
        float a0 = bias0 + Aq[(size_t)j * PAIR + p0];
        float a1 = bias1 + Aq[(size_t)j * PAIR + p1];
        #pragma unroll
        for (int c4 = 0; c4 < 8; ++c4) {
            float4 qv = q4[c4];
            a0 = fmaf(qv.x, kw0[c4*4+0], a0);
            a1 = fmaf(qv.x, kw1[c4*4+0], a1);
            a0 = fmaf(qv.y, kw0[c4*4+1], a0);
            a1 = fmaf(qv.y, kw1[c4*4+1], a1);
            a0 = fmaf(qv.z, kw0[c4*4+2], a0);
            a1 = fmaf(qv.z, kw1[c4*4+2], a1);
            a0 = fmaf(qv.w, kw0[c4*4+3], a0);
            a1 = fmaf(qv.w, kw1[c4*4+3], a1);
        }
        size_t off = ((size_t)i * LSEQ + (size_t)j) * PAIR;
        out[off + p0] = a0;
        out[off + p1] = a1;
    }
}

extern "C" void kernel_launch(void* const* d_in, const int* in_sizes, int n_in,
                              void* d_out, int out_size, void* d_ws, size_t ws_size,
                              hipStream_t stream) {
    const float* x     = (const float*)d_in[0];
    const float* gamma = (const float*)d_in[1];
    const float* beta  = (const float*)d_in[2];
    const float* pw    = (const float*)d_in[3];
    const float* pb    = (const float*)d_in[4];
    const float* ow    = (const float*)d_in[5];
    const float* ob    = (const float*)d_in[6];
    float* out = (float*)d_out;

    // workspace layout
    float* qk = (float*)d_ws;                 // 1024*64  = 256 KB
    float* Aq = qk + (size_t)LSEQ * 64;       // 1024*128 = 512 KB
    float* Ak = Aq + (size_t)LSEQ * PAIR;     // 1024*128 = 512 KB

    ln_proj_kernel<<<dim3(LSEQ), dim3(256), 0, stream>>>(
        x, gamma, beta, pw, pb, ow, qk, Aq, Ak);

    pair_kernel<<<dim3(LSEQ, 8), dim3(256), 0, stream>>>(
        qk, Aq, Ak, ow, ob, out);
}